// Round 11
// baseline (145.242 us; speedup 1.0000x reference)
//
#include <hip/hip_runtime.h>
#include <math.h>

// PhiCell hysteresis scan: s' = max(x-0.5, min(x+0.5, s)); output o_t = s_t.
// Associative scan over (lo,hi) clamp operators.
// R11: R7 structure (best verified, 92.3us; identity tile order — R10's XCD
// swizzle regressed). Changes: K2 stores DIRECT (no output LDS transpose) and
// NON-TEMPORAL (out is never re-read; don't evict K1's cached x lines).

#define T_ELEMS 8388608
#define NEG_INF (-__builtin_inff())
#define POS_INF (__builtin_inff())

#define BLOCK   256
#define WAVES   4
#define F4T     8                         // float4 per thread (32 floats)
#define F4W     (64 * F4T)                // 512 float4 per wave region
#define F4B     (BLOCK * F4T)             // 2048 float4 per block
#define EPB     (F4B * 4)                 // 8192 floats per block
#define NBLK    (T_ELEMS / EPB)           // 1024 tiles
#define APT     (NBLK / BLOCK)            // 4 agg entries per thread in K2

struct Op { float lo, hi; };
using f4v = __attribute__((ext_vector_type(4))) float;

// Apply operator a first, then b:  result(s) = b(a(s))
__device__ __forceinline__ Op combine(Op a, Op b) {
    Op r;
    r.lo = fmaxf(b.lo, fminf(b.hi, a.lo));
    r.hi = fminf(b.hi, a.hi);
    return r;
}
__device__ __forceinline__ float apply_op(Op o, float s) {
    return fmaxf(o.lo, fminf(o.hi, s));
}
__device__ __forceinline__ void fold_elem(Op& t, float e) {
    float elo = e - 0.5f, ehi = e + 0.5f;
    t.lo = fmaxf(elo, fminf(ehi, t.lo));
    t.hi = fminf(ehi, t.hi);
}
__device__ __forceinline__ void fold4(Op& t, float4 v) {
    fold_elem(t, v.x); fold_elem(t, v.y); fold_elem(t, v.z); fold_elem(t, v.w);
}
// XOR swizzle on float4 index within a 512-float4 wave region (verified R5/R7).
__device__ __forceinline__ int swz(int idx) { return idx ^ ((idx >> 3) & 7); }

// Ordered wave-inclusive scan (lane order = time order).
__device__ __forceinline__ Op wave_incl_scan(Op t, int lane) {
#pragma unroll
    for (int off = 1; off < 64; off <<= 1) {
        float nlo = __shfl_up(t.lo, off);
        float nhi = __shfl_up(t.hi, off);
        if (lane >= off) {
            Op prev = { nlo, nhi };
            t = combine(prev, t);
        }
    }
    return t;
}
// Ordered wave reduction (result valid in lane 0).
__device__ __forceinline__ Op wave_reduce(Op t) {
#pragma unroll
    for (int off = 1; off < 64; off <<= 1) {
        Op nb;
        nb.lo = __shfl_down(t.lo, off);
        nb.hi = __shfl_down(t.hi, off);
        t = combine(t, nb);
    }
    return t;
}

// Load a wave's 512-float4 slice (coalesced), scale, transpose via swizzled
// LDS so each thread holds 32 time-contiguous floats in v[0..7].
__device__ __forceinline__ void load_tile(const float4* __restrict__ xg,
                                          size_t wbase, int lane, float wv,
                                          float4* wbuf, float4 v[F4T]) {
#pragma unroll
    for (int j = 0; j < F4T; ++j) {
        float4 t = xg[wbase + j * 64 + lane];
        t.x *= wv; t.y *= wv; t.z *= wv; t.w *= wv;
        wbuf[swz(j * 64 + lane)] = t;
    }
#pragma unroll
    for (int k = 0; k < F4T; ++k)
        v[k] = wbuf[swz(lane * F4T + k)];
}

// ---------------- K1: per-block aggregate operators ----------------
__global__ __launch_bounds__(BLOCK) void k1_agg(const float* __restrict__ x,
                                                const float* __restrict__ w,
                                                float2* __restrict__ agg) {
    __shared__ float4 xbuf[WAVES * F4W];   // 32 KB
    __shared__ Op wt[WAVES];
    const int tid = threadIdx.x, lane = tid & 63, wid = tid >> 6;
    const int b = blockIdx.x;
    const float wv = w[0];

    float4* wbuf = xbuf + wid * F4W;
    const size_t wbase = (size_t)b * F4B + (size_t)wid * F4W;
    const float4* xg = reinterpret_cast<const float4*>(x);

    float4 v[F4T];
    load_tile(xg, wbase, lane, wv, wbuf, v);

    Op t = { v[0].x - 0.5f, v[0].x + 0.5f };
    fold_elem(t, v[0].y); fold_elem(t, v[0].z); fold_elem(t, v[0].w);
#pragma unroll
    for (int k = 1; k < F4T; ++k) fold4(t, v[k]);

    t = wave_reduce(t);
    if (lane == 0) wt[wid] = t;
    __syncthreads();
    if (tid == 0) {
        Op bt = wt[0];
#pragma unroll
        for (int k = 1; k < WAVES; ++k) bt = combine(bt, wt[k]);
        agg[b] = make_float2(bt.lo, bt.hi);
    }
}

// ---------------- K2: per-block prefix fold + apply + store ----------------
__global__ __launch_bounds__(BLOCK) void k2_apply(const float* __restrict__ x,
                                                  const float* __restrict__ w,
                                                  const float* __restrict__ s0,
                                                  const float2* __restrict__ agg,
                                                  float* __restrict__ out) {
    __shared__ float4 xbuf[WAVES * F4W];   // 32 KB
    __shared__ Op wtA[WAVES];              // per-wave inclusive totals (this block)
    __shared__ Op wtP[WAVES];              // prefix-fold partials
    const int tid = threadIdx.x, lane = tid & 63, wid = tid >> 6;
    const int b = blockIdx.x;
    const float wv = w[0];

    // ---- block-exclusive prefix E_b = ordered fold of agg[0..b-1] ----
    Op seg = { NEG_INF, POS_INF };
#pragma unroll
    for (int j = 0; j < APT; ++j) {
        int i = tid * APT + j;
        if (i < b) {
            float2 f = agg[i];
            Op o = { f.x, f.y };
            seg = combine(seg, o);
        }
    }
    seg = wave_reduce(seg);
    if (lane == 0) wtP[wid] = seg;

    // ---- load tile (coalesced + LDS transpose), in-block scan ----
    float4* wbuf = xbuf + wid * F4W;
    const size_t wbase = (size_t)b * F4B + (size_t)wid * F4W;
    const float4* xg = reinterpret_cast<const float4*>(x);

    float4 v[F4T];
    load_tile(xg, wbase, lane, wv, wbuf, v);

    Op t = { v[0].x - 0.5f, v[0].x + 0.5f };
    fold_elem(t, v[0].y); fold_elem(t, v[0].z); fold_elem(t, v[0].w);
#pragma unroll
    for (int k = 1; k < F4T; ++k) fold4(t, v[k]);

    Op incl = wave_incl_scan(t, lane);
    if (lane == 63) wtA[wid] = incl;
    __syncthreads();

    Op Eb = wtP[0];
#pragma unroll
    for (int k = 1; k < WAVES; ++k) Eb = combine(Eb, wtP[k]);

    Op wpre = { NEG_INF, POS_INF };
    for (int k = 0; k < wid; ++k) wpre = combine(wpre, wtA[k]);
    float elo = __shfl_up(incl.lo, 1);
    float ehi = __shfl_up(incl.hi, 1);
    Op excl;
    if (lane == 0) { excl.lo = NEG_INF; excl.hi = POS_INF; }
    else           { excl.lo = elo;     excl.hi = ehi;     }

    float s = apply_op(Eb, s0[0]);            // state entering this block
    s = apply_op(combine(wpre, excl), s);     // state entering this thread

    // ---- apply 32 elems; DIRECT non-temporal stores (per-thread 128B line;
    //      L2 write-combines; NT keeps x lines resident) ----
    f4v* og = reinterpret_cast<f4v*>(out);
    const size_t tb4 = wbase + (size_t)lane * F4T;   // thread's first float4 idx
#pragma unroll
    for (int k = 0; k < F4T; ++k) {
        float4 e = v[k];
        f4v o4;
        s = fmaxf(e.x - 0.5f, fminf(e.x + 0.5f, s)); o4.x = s;
        s = fmaxf(e.y - 0.5f, fminf(e.y + 0.5f, s)); o4.y = s;
        s = fmaxf(e.z - 0.5f, fminf(e.z + 0.5f, s)); o4.z = s;
        s = fmaxf(e.w - 0.5f, fminf(e.w + 0.5f, s)); o4.w = s;
        __builtin_nontemporal_store(o4, og + tb4 + k);
    }

    if (b == NBLK - 1 && tid == BLOCK - 1)
        out[T_ELEMS] = s;                     // final state
}

extern "C" void kernel_launch(void* const* d_in, const int* in_sizes, int n_in,
                              void* d_out, int out_size, void* d_ws, size_t ws_size,
                              hipStream_t stream) {
    const float* x  = (const float*)d_in[0];   // (1, T) f32
    const float* w  = (const float*)d_in[1];   // (1, 1) f32
    const float* s0 = (const float*)d_in[2];   // (1, 1) f32
    float* out = (float*)d_out;                // [T outputs | final state]

    float2* agg = (float2*)d_ws;               // NBLK float2 (8 KB)

    k1_agg<<<NBLK, BLOCK, 0, stream>>>(x, w, agg);
    k2_apply<<<NBLK, BLOCK, 0, stream>>>(x, w, s0, agg, out);
}

// Round 12
// 93.153 us; speedup vs baseline: 1.5592x; 1.5592x over previous
//
#include <hip/hip_runtime.h>
#include <math.h>

// PhiCell hysteresis scan: s' = max(x-0.5, min(x+0.5, s)); output o_t = s_t.
// Associative scan over (lo,hi) clamp operators.
// R12: K2 = exact R7 (best verified 92.3us: coalesced + swizzled-LDS transpose
// both directions, plain stores). K1 streamlined: no LDS, no register tile --
// ordered wave_reduce per coalesced 256-elem group, combine groups in order.
// (min/max algebra is exactly associative -> bit-identical aggregates.)
// Falsified levers (do not retry): direct strided loads (R8), XCD swizzle
// (R10), decoupled lookback (R9), NT stores (R11: 3.3x write amplification).

#define T_ELEMS 8388608
#define NEG_INF (-__builtin_inff())
#define POS_INF (__builtin_inff())

#define BLOCK   256
#define WAVES   4
#define F4T     8                         // float4 per thread (32 floats)
#define F4W     (64 * F4T)                // 512 float4 per wave region
#define F4B     (BLOCK * F4T)             // 2048 float4 per block
#define EPB     (F4B * 4)                 // 8192 floats per block
#define NBLK    (T_ELEMS / EPB)           // 1024 tiles
#define APT     (NBLK / BLOCK)            // 4 agg entries per thread in K2

struct Op { float lo, hi; };

// Apply operator a first, then b:  result(s) = b(a(s))
__device__ __forceinline__ Op combine(Op a, Op b) {
    Op r;
    r.lo = fmaxf(b.lo, fminf(b.hi, a.lo));
    r.hi = fminf(b.hi, a.hi);
    return r;
}
__device__ __forceinline__ float apply_op(Op o, float s) {
    return fmaxf(o.lo, fminf(o.hi, s));
}
__device__ __forceinline__ void fold_elem(Op& t, float e) {
    float elo = e - 0.5f, ehi = e + 0.5f;
    t.lo = fmaxf(elo, fminf(ehi, t.lo));
    t.hi = fminf(ehi, t.hi);
}
__device__ __forceinline__ void fold4(Op& t, float4 v) {
    fold_elem(t, v.x); fold_elem(t, v.y); fold_elem(t, v.z); fold_elem(t, v.w);
}
__device__ __forceinline__ Op thread_op4(float4 v) {
    Op t = { v.x - 0.5f, v.x + 0.5f };
    fold_elem(t, v.y); fold_elem(t, v.z); fold_elem(t, v.w);
    return t;
}
// XOR swizzle on float4 index within a 512-float4 wave region (verified R5/R7).
__device__ __forceinline__ int swz(int idx) { return idx ^ ((idx >> 3) & 7); }

// Ordered wave-inclusive scan (lane order = time order).
__device__ __forceinline__ Op wave_incl_scan(Op t, int lane) {
#pragma unroll
    for (int off = 1; off < 64; off <<= 1) {
        float nlo = __shfl_up(t.lo, off);
        float nhi = __shfl_up(t.hi, off);
        if (lane >= off) {
            Op prev = { nlo, nhi };
            t = combine(prev, t);
        }
    }
    return t;
}
// Ordered wave reduction (result valid in lane 0).
__device__ __forceinline__ Op wave_reduce(Op t) {
#pragma unroll
    for (int off = 1; off < 64; off <<= 1) {
        Op nb;
        nb.lo = __shfl_down(t.lo, off);
        nb.hi = __shfl_down(t.hi, off);
        t = combine(t, nb);
    }
    return t;
}

// ---------------- K1: per-block aggregates, LDS-free streaming fold --------
__global__ __launch_bounds__(BLOCK) void k1_agg(const float* __restrict__ x,
                                                const float* __restrict__ w,
                                                float2* __restrict__ agg) {
    __shared__ Op wt[WAVES];
    const int tid = threadIdx.x, lane = tid & 63, wid = tid >> 6;
    const float wv = w[0];
    const size_t wbase = (size_t)blockIdx.x * F4B + (size_t)wid * F4W;
    const float4* xg = reinterpret_cast<const float4*>(x);

    Op acc;
#pragma unroll
    for (int j = 0; j < F4T; ++j) {
        float4 t = xg[wbase + j * 64 + lane];
        t.x *= wv; t.y *= wv; t.z *= wv; t.w *= wv;
        Op o = wave_reduce(thread_op4(t));   // ordered fold of 256 contiguous elems
        acc = (j == 0) ? o : combine(acc, o);  // groups combined in time order
    }
    if (lane == 0) wt[wid] = acc;
    __syncthreads();
    if (tid == 0) {
        Op bt = wt[0];
#pragma unroll
        for (int k = 1; k < WAVES; ++k) bt = combine(bt, wt[k]);
        agg[blockIdx.x] = make_float2(bt.lo, bt.hi);
    }
}

// ---------------- K2: exact R7 (prefix fold + transpose + apply + store) ---
__global__ __launch_bounds__(BLOCK) void k2_apply(const float* __restrict__ x,
                                                  const float* __restrict__ w,
                                                  const float* __restrict__ s0,
                                                  const float2* __restrict__ agg,
                                                  float* __restrict__ out) {
    __shared__ float4 xbuf[WAVES * F4W];   // 32 KB
    __shared__ Op wtA[WAVES];              // per-wave inclusive totals (this block)
    __shared__ Op wtP[WAVES];              // prefix-fold partials
    const int tid = threadIdx.x, lane = tid & 63, wid = tid >> 6;
    const int b = blockIdx.x;
    const float wv = w[0];

    // ---- block-exclusive prefix E_b = ordered fold of agg[0..b-1] ----
    Op seg = { NEG_INF, POS_INF };
#pragma unroll
    for (int j = 0; j < APT; ++j) {
        int i = tid * APT + j;
        if (i < b) {
            float2 f = agg[i];
            Op o = { f.x, f.y };
            seg = combine(seg, o);
        }
    }
    seg = wave_reduce(seg);
    if (lane == 0) wtP[wid] = seg;

    // ---- load tile (coalesced + swizzled-LDS transpose), in-block scan ----
    float4* wbuf = xbuf + wid * F4W;
    const size_t wbase = (size_t)b * F4B + (size_t)wid * F4W;
    const float4* xg = reinterpret_cast<const float4*>(x);

    float4 v[F4T];
#pragma unroll
    for (int j = 0; j < F4T; ++j) {
        float4 t = xg[wbase + j * 64 + lane];
        t.x *= wv; t.y *= wv; t.z *= wv; t.w *= wv;
        wbuf[swz(j * 64 + lane)] = t;
    }
#pragma unroll
    for (int k = 0; k < F4T; ++k)
        v[k] = wbuf[swz(lane * F4T + k)];

    Op t = { v[0].x - 0.5f, v[0].x + 0.5f };
    fold_elem(t, v[0].y); fold_elem(t, v[0].z); fold_elem(t, v[0].w);
#pragma unroll
    for (int k = 1; k < F4T; ++k) fold4(t, v[k]);

    Op incl = wave_incl_scan(t, lane);
    if (lane == 63) wtA[wid] = incl;
    __syncthreads();

    Op Eb = wtP[0];
#pragma unroll
    for (int k = 1; k < WAVES; ++k) Eb = combine(Eb, wtP[k]);

    Op wpre = { NEG_INF, POS_INF };
    for (int k = 0; k < wid; ++k) wpre = combine(wpre, wtA[k]);
    float elo = __shfl_up(incl.lo, 1);
    float ehi = __shfl_up(incl.hi, 1);
    Op excl;
    if (lane == 0) { excl.lo = NEG_INF; excl.hi = POS_INF; }
    else           { excl.lo = elo;     excl.hi = ehi;     }

    float s = apply_op(Eb, s0[0]);            // state entering this block
    s = apply_op(combine(wpre, excl), s);     // state entering this thread

    // ---- apply 32 elems; store through the same transpose (plain stores) ----
    float4* og = reinterpret_cast<float4*>(out);
#pragma unroll
    for (int k = 0; k < F4T; ++k) {
        float4 e = v[k], o4;
        s = fmaxf(e.x - 0.5f, fminf(e.x + 0.5f, s)); o4.x = s;
        s = fmaxf(e.y - 0.5f, fminf(e.y + 0.5f, s)); o4.y = s;
        s = fmaxf(e.z - 0.5f, fminf(e.z + 0.5f, s)); o4.z = s;
        s = fmaxf(e.w - 0.5f, fminf(e.w + 0.5f, s)); o4.w = s;
        wbuf[swz(lane * F4T + k)] = o4;
    }
#pragma unroll
    for (int j = 0; j < F4T; ++j)
        og[wbase + j * 64 + lane] = wbuf[swz(j * 64 + lane)];

    if (b == NBLK - 1 && tid == BLOCK - 1)
        out[T_ELEMS] = s;                     // final state
}

extern "C" void kernel_launch(void* const* d_in, const int* in_sizes, int n_in,
                              void* d_out, int out_size, void* d_ws, size_t ws_size,
                              hipStream_t stream) {
    const float* x  = (const float*)d_in[0];   // (1, T) f32
    const float* w  = (const float*)d_in[1];   // (1, 1) f32
    const float* s0 = (const float*)d_in[2];   // (1, 1) f32
    float* out = (float*)d_out;                // [T outputs | final state]

    float2* agg = (float2*)d_ws;               // NBLK float2 (8 KB)

    k1_agg<<<NBLK, BLOCK, 0, stream>>>(x, w, agg);
    k2_apply<<<NBLK, BLOCK, 0, stream>>>(x, w, s0, agg, out);
}